// Round 13
// baseline (616.199 us; speedup 1.0000x reference)
//
#include <hip/hip_runtime.h>

// PointPillarScatter: scatter (B*P, C) pillar features into dense BEV canvas
// out[b][ch][y][x], zero elsewhere. B=8, C=64, NX=432, NY=496, NZ=1.
//
// v9: LDS-staged compose with a LOAD-FREE store loop.
// Evidence ladder: pure-store kernels (rocclr fill, r1 pps_zero_out) hit
// 6.0-6.2 TB/s; EVERY variant mixing map/pf loads into the store stream
// caps at 1.9-3.0 TB/s (r2/r5/r11/r12). vmcnt is in-order, so waiting on a
// load drains all older stores -> store-ack serialization; and with stride-53
// occupancy ~99% of waves contain an occupied lane, so the gather path runs
// in every wave. Fix: stage the ~20 occupied pillar rows per block into LDS
// up front (one-time vmcnt cost), then a pure store sweep reading only LDS
// (lgkmcnt never blocks the store queue).

#define PPS_NX   432
#define PPS_NY   496
#define PPS_GRID (PPS_NX * PPS_NY)   // 214272
#define PPS_C    64
#define PPS_B    8
#define PPS_U    (PPS_GRID / 4)      // 53568 float4-units per plane
#define SLICE_F4 256                 // float4-units per block (1024 pixels)
#define N_SLICE  ((PPS_U + SLICE_F4 - 1) / SLICE_F4)   // 210
#define MAX_SLOTS 64                 // staged pillar rows per block (exp ~20)
#define ROW_PITCH 65                 // pad 64->65 floats: avoid same-bank reads

typedef float f32x4 __attribute__((ext_vector_type(4)));

// ---- Kernel 1: init inverse map to -1 (6.86 MB) -------------------------
__global__ void pps_init_map(int4* __restrict__ map4, int n4) {
    int i = blockIdx.x * blockDim.x + threadIdx.x;
    if (i < n4) map4[i] = make_int4(-1, -1, -1, -1);
}

// ---- Kernel 2: scatter pillar indices into the map (32768 x 4 B) --------
__global__ void pps_scatter_idx(const int4* __restrict__ coords,
                                int* __restrict__ map, int P) {
    int p = blockIdx.x * blockDim.x + threadIdx.x;
    if (p >= P) return;
    int4 c = coords[p];   // (batch, z, y, x)
    int pos = c.y + c.z * PPS_NX + c.w;           // in-plane index
    map[c.x * PPS_GRID + pos] = p;
}

// ---- Kernel 3: LDS-staged compose, load-free store sweep ----------------
// Block = (batch b, u-slice of SLICE_F4 float4s) x all 64 planes (256 KB out).
// Phase 1: map slice -> regs; occupied pillars -> LDS slots; gather rows.
// Phase 2: per plane one float4 store/thread. No global loads in the loop.
__global__ __launch_bounds__(256) void pps_compose(const float* __restrict__ pf,
                                                   const int* __restrict__ map,
                                                   f32x4* __restrict__ out4) {
    __shared__ float rows[MAX_SLOTS * ROW_PITCH];   // 16.6 KB
    __shared__ int   slotPillar[MAX_SLOTS];
    __shared__ int   nSlots;

    const int slice = blockIdx.x;
    const int b     = blockIdx.y;
    const int t     = threadIdx.x;
    const int u     = slice * SLICE_F4 + t;
    const bool inb  = (u < PPS_U);

    if (t == 0) nSlots = 0;

    int4 m = make_int4(-1, -1, -1, -1);
    if (inb) m = ((const int4*)(map + (size_t)b * PPS_GRID))[u];
    __syncthreads();   // nSlots ready; m load latency overlaps barrier

    // Assign LDS slots for this thread's occupied pixels (~20 total/block).
    int s0 = -1, s1 = -1, s2 = -1, s3 = -1;
    if (m.x >= 0) { int s = atomicAdd(&nSlots, 1); if (s < MAX_SLOTS) { slotPillar[s] = m.x; s0 = s; } else s0 = -2; }
    if (m.y >= 0) { int s = atomicAdd(&nSlots, 1); if (s < MAX_SLOTS) { slotPillar[s] = m.y; s1 = s; } else s1 = -2; }
    if (m.z >= 0) { int s = atomicAdd(&nSlots, 1); if (s < MAX_SLOTS) { slotPillar[s] = m.z; s2 = s; } else s2 = -2; }
    if (m.w >= 0) { int s = atomicAdd(&nSlots, 1); if (s < MAX_SLOTS) { slotPillar[s] = m.w; s3 = s; } else s3 = -2; }
    __syncthreads();

    // Cooperative gather of occupied pillar rows (contiguous 256 B each).
    int S = nSlots; if (S > MAX_SLOTS) S = MAX_SLOTS;
    for (int idx = t; idx < S * 16; idx += 256) {
        int slot = idx >> 4, j = idx & 15;
        f32x4 r = ((const f32x4*)pf)[(size_t)slotPillar[slot] * 16 + j];
        float* dst = rows + slot * ROW_PITCH + j * 4;
        dst[0] = r.x; dst[1] = r.y; dst[2] = r.z; dst[3] = r.w;
    }
    __syncthreads();

    if (!inb) return;

    size_t base = (size_t)b * (64 * (size_t)PPS_U) + u;
    const f32x4 z4 = {0.f, 0.f, 0.f, 0.f};

    if (((s0 & s1) & (s2 & s3)) == -1) {
        // ---- all-empty (~92% of threads): pure zero store sweep ----
        #pragma unroll
        for (int ch = 0; ch < PPS_C; ++ch) {
            out4[base] = z4;
            base += PPS_U;
        }
    } else {
        // ---- compose from LDS (global loads only on slot overflow,
        //      which never triggers at this occupancy) ----
        for (int ch = 0; ch < PPS_C; ++ch) {
            f32x4 v = z4;
            if (s0 >= 0) v.x = rows[s0 * ROW_PITCH + ch];
            else if (s0 == -2) v.x = pf[(size_t)m.x * PPS_C + ch];
            if (s1 >= 0) v.y = rows[s1 * ROW_PITCH + ch];
            else if (s1 == -2) v.y = pf[(size_t)m.y * PPS_C + ch];
            if (s2 >= 0) v.z = rows[s2 * ROW_PITCH + ch];
            else if (s2 == -2) v.z = pf[(size_t)m.z * PPS_C + ch];
            if (s3 >= 0) v.w = rows[s3 * ROW_PITCH + ch];
            else if (s3 == -2) v.w = pf[(size_t)m.w * PPS_C + ch];
            out4[base] = v;
            base += PPS_U;
        }
    }
}

// ---- Fallback (ws too small): zero + direct scatter ---------------------
__global__ void pps_zero_out(float4* __restrict__ out, long long n4) {
    long long i = (long long)blockIdx.x * blockDim.x + threadIdx.x;
    const long long stride = (long long)gridDim.x * blockDim.x;
    const float4 z = make_float4(0.f, 0.f, 0.f, 0.f);
    for (; i < n4; i += stride) out[i] = z;
}
__global__ void pps_scatter_feat(const float* __restrict__ pf,
                                 const int4* __restrict__ coords,
                                 float* __restrict__ out, int P) {
    int t = blockIdx.x * blockDim.x + threadIdx.x;
    int p = t >> 6;
    if (p >= P) return;
    int ch = t & 63;
    int4 c = coords[p];
    long long pos = (long long)c.x * (long long)(PPS_C * PPS_GRID)
                  + (long long)ch * PPS_GRID
                  + (long long)(c.y + c.z * PPS_NX + c.w);
    out[pos] = pf[t];
}

extern "C" void kernel_launch(void* const* d_in, const int* in_sizes, int n_in,
                              void* d_out, int out_size, void* d_ws, size_t ws_size,
                              hipStream_t stream) {
    const float* pf     = (const float*)d_in[0];
    const int4*  coords = (const int4*)d_in[1];
    float*       out    = (float*)d_out;
    int P = in_sizes[0] / PPS_C;   // B * P_PER = 32768

    const size_t map_bytes = (size_t)PPS_B * PPS_GRID * sizeof(int);
    if (ws_size >= map_bytes) {
        int* map = (int*)d_ws;
        int n4 = PPS_B * (PPS_GRID / 4);              // 428544 int4 entries
        pps_init_map<<<(n4 + 255) / 256, 256, 0, stream>>>((int4*)map, n4);
        pps_scatter_idx<<<(P + 255) / 256, 256, 0, stream>>>(coords, map, P);
        dim3 grid(N_SLICE, PPS_B);                    // 210 x 8 = 1680 blocks
        pps_compose<<<grid, 256, 0, stream>>>(pf, map, (f32x4*)out);
    } else {
        long long n4 = (long long)out_size / 4;
        pps_zero_out<<<2048, 256, 0, stream>>>((float4*)out, n4);
        int threads = P * PPS_C;
        pps_scatter_feat<<<(threads + 255) / 256, 256, 0, stream>>>(pf, coords, out, P);
    }
}

// Round 14
// 435.822 us; speedup vs baseline: 1.4139x; 1.4139x over previous
//
#include <hip/hip_runtime.h>

// PointPillarScatter: scatter (B*P, C) pillar features into dense BEV canvas
// out[b][ch][y][x], zero elsewhere. B=8, C=64, NX=432, NY=496, NZ=1.
//
// v10: LDS-staged compose, UNIFORM store sweep (no divergent store paths).
// Evidence ladder:
//  - pure-store kernels (rocclr fill, r1 zero_out) = 6.0-6.2 TB/s
//  - loads mixed into store stream (r2/r5/r12) = 2.3-3.0 TB/s
//  - strided/partial-line store instructions (r4 NT, r11) = 1.8-1.9 TB/s
//  - r13 divergent fast/compose split = ~1.4 TB/s: nearly every wave ran
//    BOTH branches under exec masks -> holey 1KB stores (partial-line RMW)
//    + isolated 16B compose stores. Lesson: one unconditional full-wave
//    store per location; compose the VALUE branchlessly.
// v10: stage occupied pillar rows (~20/block) in LDS once, then per plane
// ONE store/thread, value = clamped LDS read + cndmask select. Store loop
// has zero global loads and zero per-lane branches.

#define PPS_NX   432
#define PPS_NY   496
#define PPS_GRID (PPS_NX * PPS_NY)   // 214272
#define PPS_C    64
#define PPS_B    8
#define PPS_U    (PPS_GRID / 4)      // 53568 float4-units per plane
#define SLICE_F4 256                 // float4-units per block (1024 pixels)
#define N_SLICE  ((PPS_U + SLICE_F4 - 1) / SLICE_F4)   // 210
#define MAX_SLOTS 64                 // staged rows/block (expect ~20, bound ~22)
#define ROW_PITCH 65                 // 64->65 floats: distinct-s reads spread banks

typedef float f32x4 __attribute__((ext_vector_type(4)));

// ---- Kernel 1: init inverse map to -1 (6.86 MB) -------------------------
__global__ void pps_init_map(int4* __restrict__ map4, int n4) {
    int i = blockIdx.x * blockDim.x + threadIdx.x;
    if (i < n4) map4[i] = make_int4(-1, -1, -1, -1);
}

// ---- Kernel 2: scatter pillar indices into the map (32768 x 4 B) --------
__global__ void pps_scatter_idx(const int4* __restrict__ coords,
                                int* __restrict__ map, int P) {
    int p = blockIdx.x * blockDim.x + threadIdx.x;
    if (p >= P) return;
    int4 c = coords[p];   // (batch, z, y, x)
    int pos = c.y + c.z * PPS_NX + c.w;           // in-plane index
    map[c.x * PPS_GRID + pos] = p;
}

// ---- Kernel 3: LDS-staged compose, uniform store sweep ------------------
__global__ __launch_bounds__(256) void pps_compose2(const float* __restrict__ pf,
                                                    const int* __restrict__ map,
                                                    f32x4* __restrict__ out4) {
    __shared__ float rows[MAX_SLOTS * ROW_PITCH];   // 16.6 KB
    __shared__ int   slotPillar[MAX_SLOTS];
    __shared__ int   nSlots;

    const int slice = blockIdx.x;
    const int b     = blockIdx.y;
    const int t     = threadIdx.x;
    const int u     = slice * SLICE_F4 + t;
    const bool inb  = (u < PPS_U);

    if (t == 0) nSlots = 0;

    int4 m = make_int4(-1, -1, -1, -1);
    if (inb) m = ((const int4*)(map + (size_t)b * PPS_GRID))[u];
    __syncthreads();   // nSlots=0 visible; map-load latency overlaps barrier

    // Slot assignment for this thread's occupied pixels (~20/block total).
    int s0 = -1, s1 = -1, s2 = -1, s3 = -1;
    if (m.x >= 0) { int s = atomicAdd(&nSlots, 1); if (s < MAX_SLOTS) { slotPillar[s] = m.x; s0 = s; } else s0 = -2; }
    if (m.y >= 0) { int s = atomicAdd(&nSlots, 1); if (s < MAX_SLOTS) { slotPillar[s] = m.y; s1 = s; } else s1 = -2; }
    if (m.z >= 0) { int s = atomicAdd(&nSlots, 1); if (s < MAX_SLOTS) { slotPillar[s] = m.z; s2 = s; } else s2 = -2; }
    if (m.w >= 0) { int s = atomicAdd(&nSlots, 1); if (s < MAX_SLOTS) { slotPillar[s] = m.w; s3 = s; } else s3 = -2; }
    __syncthreads();

    // Cooperative gather of occupied pillar rows (contiguous 256 B each).
    int S = nSlots; if (S > MAX_SLOTS) S = MAX_SLOTS;
    for (int idx = t; idx < S * 16; idx += 256) {
        int slot = idx >> 4, j = idx & 15;
        f32x4 r = ((const f32x4*)pf)[(size_t)slotPillar[slot] * 16 + j];
        float* dst = rows + slot * ROW_PITCH + j * 4;
        dst[0] = r.x; dst[1] = r.y; dst[2] = r.z; dst[3] = r.w;
    }
    __syncthreads();

    if (!inb) return;

    size_t base = (size_t)b * (64 * (size_t)PPS_U) + u;
    const f32x4 z4 = {0.f, 0.f, 0.f, 0.f};
    const bool occ = (m.x & m.y & m.z & m.w) >= 0;   // any of 4 occupied

    if (!__any(occ)) {
        // Wave-uniform all-empty (~0.6% of waves): pure zero sweep.
        #pragma unroll
        for (int ch = 0; ch < PPS_C; ++ch) { out4[base] = z4; base += PPS_U; }
        return;
    }

    // Unified branchless sweep: one unconditional store per plane; value
    // from clamped-address LDS reads + selects. No global loads, no holes.
    const int r0 = (s0 < 0) ? 0 : s0;
    const int r1 = (s1 < 0) ? 0 : s1;
    const int r2 = (s2 < 0) ? 0 : s2;
    const int r3 = (s3 < 0) ? 0 : s3;
    #pragma unroll 8
    for (int ch = 0; ch < PPS_C; ++ch) {
        f32x4 v;
        v.x = (s0 >= 0) ? rows[r0 * ROW_PITCH + ch] : 0.f;
        v.y = (s1 >= 0) ? rows[r1 * ROW_PITCH + ch] : 0.f;
        v.z = (s2 >= 0) ? rows[r2 * ROW_PITCH + ch] : 0.f;
        v.w = (s3 >= 0) ? rows[r3 * ROW_PITCH + ch] : 0.f;
        // slot-overflow fallback (never triggers at ~20 slots/block)
        if (s0 == -2) v.x = pf[(size_t)m.x * PPS_C + ch];
        if (s1 == -2) v.y = pf[(size_t)m.y * PPS_C + ch];
        if (s2 == -2) v.z = pf[(size_t)m.z * PPS_C + ch];
        if (s3 == -2) v.w = pf[(size_t)m.w * PPS_C + ch];
        out4[base] = v;
        base += PPS_U;
    }
}

// ---- Fallback (ws too small): zero + direct scatter ---------------------
__global__ void pps_zero_out(float4* __restrict__ out, long long n4) {
    long long i = (long long)blockIdx.x * blockDim.x + threadIdx.x;
    const long long stride = (long long)gridDim.x * blockDim.x;
    const float4 z = make_float4(0.f, 0.f, 0.f, 0.f);
    for (; i < n4; i += stride) out[i] = z;
}
__global__ void pps_scatter_feat(const float* __restrict__ pf,
                                 const int4* __restrict__ coords,
                                 float* __restrict__ out, int P) {
    int t = blockIdx.x * blockDim.x + threadIdx.x;
    int p = t >> 6;
    if (p >= P) return;
    int ch = t & 63;
    int4 c = coords[p];
    long long pos = (long long)c.x * (long long)(PPS_C * PPS_GRID)
                  + (long long)ch * PPS_GRID
                  + (long long)(c.y + c.z * PPS_NX + c.w);
    out[pos] = pf[t];
}

extern "C" void kernel_launch(void* const* d_in, const int* in_sizes, int n_in,
                              void* d_out, int out_size, void* d_ws, size_t ws_size,
                              hipStream_t stream) {
    const float* pf     = (const float*)d_in[0];
    const int4*  coords = (const int4*)d_in[1];
    float*       out    = (float*)d_out;
    int P = in_sizes[0] / PPS_C;   // B * P_PER = 32768

    const size_t map_bytes = (size_t)PPS_B * PPS_GRID * sizeof(int);
    if (ws_size >= map_bytes) {
        int* map = (int*)d_ws;
        int n4 = PPS_B * (PPS_GRID / 4);              // 428544 int4 entries
        pps_init_map<<<(n4 + 255) / 256, 256, 0, stream>>>((int4*)map, n4);
        pps_scatter_idx<<<(P + 255) / 256, 256, 0, stream>>>(coords, map, P);
        dim3 grid(N_SLICE, PPS_B);                    // 210 x 8 = 1680 blocks
        pps_compose2<<<grid, 256, 0, stream>>>(pf, map, (f32x4*)out);
    } else {
        long long n4 = (long long)out_size / 4;
        pps_zero_out<<<2048, 256, 0, stream>>>((float4*)out, n4);
        int threads = P * PPS_C;
        pps_scatter_feat<<<(threads + 255) / 256, 256, 0, stream>>>(pf, coords, out, P);
    }
}